// Round 14
// baseline (8382.146 us; speedup 1.0000x reference)
//
#include <hip/hip_runtime.h>
#include <stdint.h>

#define TT 512
#define BB 64
#define NTAGS 48

typedef __attribute__((ext_vector_type(8))) short bf16x8;
typedef __attribute__((ext_vector_type(4))) float f32x4;
typedef __attribute__((ext_vector_type(4))) unsigned short u16x4;

__device__ inline unsigned short f2bf(float f) {
  union { float f; unsigned u; } v; v.f = f;
  unsigned r = v.u + 0x7fffu + ((v.u >> 16) & 1u);
  return (unsigned short)(r >> 16);
}
__device__ inline float bf2f(unsigned short u) {
  union { unsigned u; float f; } v; v.u = ((unsigned)u) << 16; return v.f;
}
__device__ inline float sigf(float x) { return 1.0f / (1.0f + __expf(-x)); }
__device__ inline float tanhfast(float x) { return 1.0f - 2.0f / (__expf(2.0f * x) + 1.0f); }

// ---- x[t][b][k] = bf16(embed[seq[b][t]][k]) ----
__global__ void k_gather_x(const float* __restrict__ emb, const int* __restrict__ seq,
                           unsigned short* __restrict__ x) {
  size_t i4 = ((size_t)blockIdx.x * 256 + threadIdx.x) * 4;  // < T*B*512
  int r = (int)(i4 >> 9);
  int k = (int)(i4 & 511);
  int t = r >> 6, b = r & 63;
  int tok = seq[b * TT + t];
  float4 v = *(const float4*)(emb + (size_t)tok * 512 + k);
  unsigned short* dst = x + i4;
  dst[0] = f2bf(v.x); dst[1] = f2bf(v.y); dst[2] = f2bf(v.z); dst[3] = f2bf(v.w);
}

// ---- generic f32 -> bf16 convert, 4 elems/thread ----
__global__ void k_conv(const float* __restrict__ s, unsigned short* __restrict__ d, int n4) {
  int i = blockIdx.x * 256 + threadIdx.x;
  if (i >= n4) return;
  float4 v = *(const float4*)(s + (size_t)i * 4);
  unsigned short* dst = d + (size_t)i * 4;
  dst[0] = f2bf(v.x); dst[1] = f2bf(v.y); dst[2] = f2bf(v.z); dst[3] = f2bf(v.w);
}

// ---- bias sums + initial h (bf16 parity-0) + initial c (f32 cbuf) ----
__global__ void k_misc2(const float* __restrict__ h0, const float* __restrict__ h1,
                        const float* __restrict__ c0, const float* __restrict__ c1,
                        const float* __restrict__ bi1f, const float* __restrict__ bh1f,
                        const float* __restrict__ bi1b, const float* __restrict__ bh1b,
                        const float* __restrict__ bi2f, const float* __restrict__ bh2f,
                        const float* __restrict__ bi2b, const float* __restrict__ bh2b,
                        float* __restrict__ bs1, float* __restrict__ bs2,
                        unsigned short* __restrict__ hb1, unsigned short* __restrict__ hb2,
                        float* __restrict__ cb1, float* __restrict__ cb2) {
  int i = blockIdx.x * 256 + threadIdx.x;
  if (i < 4096) { int dd = i >> 11, n = i & 2047; bs1[i] = dd ? (bi1b[n] + bh1b[n]) : (bi1f[n] + bh1f[n]); return; }
  i -= 4096;
  if (i < 2048) { int dd = i >> 10, n = i & 1023; bs2[i] = dd ? (bi2b[n] + bh2b[n]) : (bi2f[n] + bh2f[n]); return; }
  i -= 2048;
  if (i < 65536) { hb1[i] = f2bf(h0[i]); return; }   // hbuf1 parity 0: [2][64][512]
  i -= 65536;
  if (i < 32768) { hb2[i] = f2bf(h1[i]); return; }   // hbuf2 parity 0: [2][64][256]
  i -= 32768;
  if (i < 65536) { cb1[i] = c0[i]; return; }         // cbuf1: [2][64][512]
  i -= 65536;
  if (i < 32768) { cb2[i] = c1[i]; return; }         // cbuf2: [2][64][256]
}

// ======================= PRIMARY PATH (chunked xp) =======================
// xp[sc][dir][ug][g][bt][lane*4+rr] bf16, bias folded in.  8KB per (sc,dir,ug).
template<int KX, int H>
__global__ __launch_bounds__(512) void k_xproj_c(
    const unsigned short* __restrict__ xin, const unsigned short* __restrict__ Wih,
    const float* __restrict__ bsum, unsigned short* __restrict__ xp, int s0) {
  const int UG = H / 16;
  int wid = blockIdx.x * 8 + (threadIdx.x >> 6);
  const int lane = threadIdx.x & 63;
  const int ug = wid % UG; wid /= UG;
  const int g = wid & 3; wid >>= 2;
  const int dir = wid & 1; wid >>= 1;
  const int sc = wid;
  const int s = s0 + sc;
  const int t = dir ? (TT - 1 - s) : s;
  const int r16 = lane & 15, kg = lane >> 4;
  const int rowg = dir * 4 * H + g * H + ug * 16 + r16;
  const unsigned short* wrow = Wih + (size_t)rowg * KX + kg * 8;
  const float bias = bsum[rowg];
  const unsigned short* xa = xin + (size_t)t * 64 * KX + kg * 8;
  f32x4 A0 = {bias, bias, bias, bias}, A1 = A0, A2 = A0, A3 = A0;
  #pragma unroll
  for (int kc = 0; kc < KX / 128; ++kc) {
    bf16x8 wv_[4], av_[4][4];
    #pragma unroll
    for (int u = 0; u < 4; ++u) {
      const int kk = kc * 4 + u;
      wv_[u] = *(const bf16x8*)(wrow + kk * 32);
      av_[u][0] = *(const bf16x8*)(xa + (size_t)(0 * 16 + r16) * KX + kk * 32);
      av_[u][1] = *(const bf16x8*)(xa + (size_t)(1 * 16 + r16) * KX + kk * 32);
      av_[u][2] = *(const bf16x8*)(xa + (size_t)(2 * 16 + r16) * KX + kk * 32);
      av_[u][3] = *(const bf16x8*)(xa + (size_t)(3 * 16 + r16) * KX + kk * 32);
    }
    #pragma unroll
    for (int u = 0; u < 4; ++u) {
      A0 = __builtin_amdgcn_mfma_f32_16x16x32_bf16(av_[u][0], wv_[u], A0, 0, 0, 0);
      A1 = __builtin_amdgcn_mfma_f32_16x16x32_bf16(av_[u][1], wv_[u], A1, 0, 0, 0);
      A2 = __builtin_amdgcn_mfma_f32_16x16x32_bf16(av_[u][2], wv_[u], A2, 0, 0, 0);
      A3 = __builtin_amdgcn_mfma_f32_16x16x32_bf16(av_[u][3], wv_[u], A3, 0, 0, 0);
    }
  }
  unsigned short* dst = xp + ((((size_t)sc * 2 + dir) * UG + ug) * 4 + g) * 1024 + lane * 4;
  u16x4 s0v = {f2bf(A0[0]), f2bf(A0[1]), f2bf(A0[2]), f2bf(A0[3])};
  u16x4 s1v = {f2bf(A1[0]), f2bf(A1[1]), f2bf(A1[2]), f2bf(A1[3])};
  u16x4 s2v = {f2bf(A2[0]), f2bf(A2[1]), f2bf(A2[2]), f2bf(A2[3])};
  u16x4 s3v = {f2bf(A3[0]), f2bf(A3[1]), f2bf(A3[2]), f2bf(A3[3])};
  *(u16x4*)(dst + 0)   = s0v;
  *(u16x4*)(dst + 256) = s1v;
  *(u16x4*)(dst + 512) = s2v;
  *(u16x4*)(dst + 768) = s3v;
}

// ---- recurrent chunk kernel, DECOUPLED WAVES + REGISTER-RESIDENT Whh:
// no LDS in the kernel at all (no staging, no bank conflicts, no __syncthreads);
// per-(dir,bt,ug) flags; RELAXED+AGENT atomics; producer drains h then flags.
template<int H, int NBLKD, int CHN>
__global__ __launch_bounds__(256, 1) void k_lstm_c(
    const unsigned short* __restrict__ xp,    // [CHN][2][UG][4][4][256] bf16
    const unsigned short* __restrict__ Whh,   // [2][4H][H] bf16
    float* __restrict__ cbuf,                 // [2][64][H] f32 (chunk handoff)
    unsigned short* __restrict__ hbuf,        // [2 parity][2 dir][64][H] bf16
    unsigned short* __restrict__ outp,        // [T][64][2H] bf16
    unsigned* __restrict__ arr, int s0) {     // [2 dir][4 bt][NBLKD] flags (16B stride)
  const int UG = H / 16;
  const int dir = blockIdx.x / NBLKD;
  const int ug  = blockIdx.x % NBLKD;
  const int bt = threadIdx.x >> 6, lane = threadIdx.x & 63;
  const int r16 = lane & 15, kg = lane >> 4;

  // ---- Whh fragments into registers (step-invariant; 256/128 VGPR) ----
  bf16x8 wreg[4][H / 32];
  #pragma unroll
  for (int g = 0; g < 4; ++g) {
    const unsigned short* wrow = Whh + ((size_t)(dir * 4 * H + g * H + ug * 16 + r16)) * H + kg * 8;
    #pragma unroll
    for (int kk = 0; kk < H / 32; ++kk)
      wreg[g][kk] = *(const bf16x8*)(wrow + kk * 32);
  }

  const int batch0 = bt * 16 + kg * 4;
  float creg[4];
  #pragma unroll
  for (int rr = 0; rr < 4; ++rr)
    creg[rr] = cbuf[((size_t)dir * 64 + batch0 + rr) * H + ug * 16 + r16];

  unsigned* const grp    = arr + (size_t)(dir * 4 + bt) * NBLKD * 4;  // this wave's flag group
  unsigned* const myflag = grp + (size_t)ug * 4;

  auto xpb = [&](int sc) -> const unsigned short* {
    return xp + (((size_t)sc * 2 + dir) * UG + ug) * 4096 + bt * 256 + lane * 4;
  };
  const unsigned short* pb = xpb(0);
  u16x4 px0 = *(const u16x4*)(pb + 0);
  u16x4 px1 = *(const u16x4*)(pb + 1024);
  u16x4 px2 = *(const u16x4*)(pb + 2048);
  u16x4 px3 = *(const u16x4*)(pb + 3072);

  for (int sc = 0; sc < CHN; ++sc) {
    const int s = s0 + sc;
    const int p = s & 1;
    // gate accumulators from prefetched xproj (bias folded in)
    f32x4 A0, A1, A2, A3;
    #pragma unroll
    for (int rr = 0; rr < 4; ++rr) {
      A0[rr] = bf2f(px0[rr]);
      A1[rr] = bf2f(px1[rr]);
      A2[rr] = bf2f(px2[rr]);
      A3[rr] = bf2f(px3[rr]);
    }
    if (sc + 1 < CHN) {  // prefetch next step's xp (plain loads, L2-cacheable)
      pb = xpb(sc + 1);
      px0 = *(const u16x4*)(pb + 0);
      px1 = *(const u16x4*)(pb + 1024);
      px2 = *(const u16x4*)(pb + 2048);
      px3 = *(const u16x4*)(pb + 3072);
    }
    // ---- wait: all NBLKD producers of (dir,bt) finished step s-1 ----
    if (s > 0) {
      const unsigned* ap = grp + (size_t)lane * 4;
      const bool act = lane < NBLKD;
      for (;;) {
        unsigned vv = act ? __hip_atomic_load(ap, __ATOMIC_RELAXED, __HIP_MEMORY_SCOPE_AGENT)
                          : 0xffffffffu;
        if (__all(vv >= (unsigned)s)) break;
        __builtin_amdgcn_s_sleep(1);
      }
      asm volatile("" ::: "memory");  // keep h loads below the poll
    }
    // ---- h loads for this wave's batch tile: independent 8B coherent loads ----
    const unsigned short* hrow = hbuf + (((size_t)p * 2 + dir) * 64 + bt * 16 + r16) * H + kg * 8;
    bf16x8 hreg[H / 32];
    #pragma unroll
    for (int kk = 0; kk < H / 32; ++kk) {
      union { bf16x8 v; unsigned long long q[2]; } hu;
      hu.q[0] = __hip_atomic_load((const unsigned long long*)(hrow + kk * 32), __ATOMIC_RELAXED, __HIP_MEMORY_SCOPE_AGENT);
      hu.q[1] = __hip_atomic_load((const unsigned long long*)(hrow + kk * 32 + 4), __ATOMIC_RELAXED, __HIP_MEMORY_SCOPE_AGENT);
      hreg[kk] = hu.v;
    }
    #pragma unroll
    for (int kk = 0; kk < H / 32; ++kk) {
      A0 = __builtin_amdgcn_mfma_f32_16x16x32_bf16(hreg[kk], wreg[0][kk], A0, 0, 0, 0);
      A1 = __builtin_amdgcn_mfma_f32_16x16x32_bf16(hreg[kk], wreg[1][kk], A1, 0, 0, 0);
      A2 = __builtin_amdgcn_mfma_f32_16x16x32_bf16(hreg[kk], wreg[2][kk], A2, 0, 0, 0);
      A3 = __builtin_amdgcn_mfma_f32_16x16x32_bf16(hreg[kk], wreg[3][kk], A3, 0, 0, 0);
    }
    const int t = dir ? (TT - 1 - s) : s;
    unsigned short* hw = hbuf + ((size_t)(p ^ 1) * 2 + dir) * 64 * H;
    unsigned short hbv[4];
    #pragma unroll
    for (int rr = 0; rr < 4; ++rr) {
      float cn = sigf(A1[rr]) * creg[rr] + sigf(A0[rr]) * tanhfast(A2[rr]);
      float hn = sigf(A3[rr]) * tanhfast(cn);
      creg[rr] = cn;
      hbv[rr] = f2bf(hn);
      __hip_atomic_store(hw + (size_t)(batch0 + rr) * H + ug * 16 + r16, hbv[rr],
                         __ATOMIC_RELAXED, __HIP_MEMORY_SCOPE_AGENT);
    }
    asm volatile("s_waitcnt vmcnt(0)" ::: "memory");  // h stores at coherence point
    if (lane == 0)
      __hip_atomic_store(myflag, (unsigned)(s + 1), __ATOMIC_RELAXED, __HIP_MEMORY_SCOPE_AGENT);
    #pragma unroll
    for (int rr = 0; rr < 4; ++rr)   // outp after flag; drains overlapped next step
      outp[((size_t)t * 64 + batch0 + rr) * (2 * H) + dir * H + ug * 16 + r16] = hbv[rr];
  }
  // chunk handoff (per-wave, disjoint)
  #pragma unroll
  for (int rr = 0; rr < 4; ++rr)
    cbuf[((size_t)dir * 64 + batch0 + rr) * H + ug * 16 + r16] = creg[rr];
}

// ======================= FALLBACK PATH (round-5, proven; small ws) =======================
template<int KX, int H, int NBLKD>
__global__ __launch_bounds__(512, 2) void k_lstm(
    const unsigned short* __restrict__ xin, const unsigned short* __restrict__ Wih,
    const unsigned short* __restrict__ Whh, const float* __restrict__ bsum,
    const float* __restrict__ cinit, unsigned short* __restrict__ hbuf,
    unsigned short* __restrict__ outp, unsigned* __restrict__ arr) {
  const int dir = blockIdx.x / NBLKD;
  const int ug  = blockIdx.x % NBLKD;
  const int wv = threadIdx.x >> 6, lane = threadIdx.x & 63;
  const int r16 = lane & 15, kg = lane >> 4;
  __shared__ unsigned short Wl[64 * H];
  __shared__ float xacc[2][4][4][256];
  __shared__ unsigned done[2];
  __shared__ int ready;
  if (threadIdx.x == 0) { done[0] = 0u; done[1] = 0u; ready = -1; }
  for (int c = threadIdx.x; c < 64 * (H / 8); c += 512) {
    const int lrow = c / (H / 8), k8 = c % (H / 8);
    bf16x8 v = *(const bf16x8*)(Whh + ((size_t)(dir * 4 * H + (lrow >> 4) * H + ug * 16 + (lrow & 15))) * H + k8 * 8);
    const int addr = ((lrow * H + k8 * 8) * 2) ^ ((lrow & 7) << 4);
    *(bf16x8*)((char*)Wl + addr) = v;
  }
  float creg[4];
  auto xgemm = [&](int sn) {
    const int gg = wv - 4;
    const int rowg = dir * 4 * H + gg * H + ug * 16 + r16;
    const unsigned short* wrow = Wih + (size_t)rowg * KX + kg * 8;
    const float bias = bsum[rowg];
    const int t = dir ? (TT - 1 - sn) : sn;
    const unsigned short* xa = xin + (size_t)t * 64 * KX + kg * 8;
    f32x4 A0 = {bias, bias, bias, bias}, A1 = A0, A2 = A0, A3 = A0;
    #pragma unroll
    for (int kc = 0; kc < KX / 128; ++kc) {
      bf16x8 wv_[4], av_[4][4];
      #pragma unroll
      for (int u = 0; u < 4; ++u) {
        const int kk = kc * 4 + u;
        wv_[u] = *(const bf16x8*)(wrow + kk * 32);
        av_[u][0] = *(const bf16x8*)(xa + (size_t)(0 * 16 + r16) * KX + kk * 32);
        av_[u][1] = *(const bf16x8*)(xa + (size_t)(1 * 16 + r16) * KX + kk * 32);
        av_[u][2] = *(const bf16x8*)(xa + (size_t)(2 * 16 + r16) * KX + kk * 32);
        av_[u][3] = *(const bf16x8*)(xa + (size_t)(3 * 16 + r16) * KX + kk * 32);
      }
      #pragma unroll
      for (int u = 0; u < 4; ++u) {
        A0 = __builtin_amdgcn_mfma_f32_16x16x32_bf16(av_[u][0], wv_[u], A0, 0, 0, 0);
        A1 = __builtin_amdgcn_mfma_f32_16x16x32_bf16(av_[u][1], wv_[u], A1, 0, 0, 0);
        A2 = __builtin_amdgcn_mfma_f32_16x16x32_bf16(av_[u][2], wv_[u], A2, 0, 0, 0);
        A3 = __builtin_amdgcn_mfma_f32_16x16x32_bf16(av_[u][3], wv_[u], A3, 0, 0, 0);
      }
    }
    const int p = sn & 1;
    *(f32x4*)&xacc[p][gg][0][lane * 4] = A0;
    *(f32x4*)&xacc[p][gg][1][lane * 4] = A1;
    *(f32x4*)&xacc[p][gg][2][lane * 4] = A2;
    *(f32x4*)&xacc[p][gg][3][lane * 4] = A3;
  };
  if (wv < 4) {
    const int batch0 = wv * 16 + kg * 4;
    #pragma unroll
    for (int rr = 0; rr < 4; ++rr)
      creg[rr] = cinit[((size_t)dir * 64 + batch0 + rr) * H + ug * 16 + r16];
  } else {
    xgemm(0);
  }
  for (int s = 0; s < TT; ++s) {
    __syncthreads();
    if (wv >= 4) {
      if (s + 1 < TT) xgemm(s + 1);
    } else {
      const int p = s & 1;
      const int bt = wv;
      f32x4 A0 = *(const f32x4*)&xacc[p][0][bt][lane * 4];
      f32x4 A1 = *(const f32x4*)&xacc[p][1][bt][lane * 4];
      f32x4 A2 = *(const f32x4*)&xacc[p][2][bt][lane * 4];
      f32x4 A3 = *(const f32x4*)&xacc[p][3][bt][lane * 4];
      const unsigned short* hrow = hbuf + (((size_t)p * 2 + dir) * 64 + bt * 16 + r16) * H + kg * 8;
      if (s > 0) {
        if (wv == 0) {
          const unsigned* ap = arr + ((size_t)dir * NBLKD + lane) * 4;
          const bool act = lane < NBLKD;
          for (;;) {
            unsigned vv = act ? __hip_atomic_load(ap, __ATOMIC_RELAXED, __HIP_MEMORY_SCOPE_AGENT)
                              : 0xffffffffu;
            if (__all(vv >= (unsigned)s)) break;
            __builtin_amdgcn_s_sleep(4);
          }
          if (lane == 0) __hip_atomic_store(&ready, s, __ATOMIC_RELAXED, __HIP_MEMORY_SCOPE_WORKGROUP);
        } else {
          while (__hip_atomic_load(&ready, __ATOMIC_RELAXED, __HIP_MEMORY_SCOPE_WORKGROUP) < s)
            __builtin_amdgcn_s_sleep(1);
        }
        asm volatile("" ::: "memory");
      }
      bf16x8 hreg[H / 32];
      #pragma unroll
      for (int kk = 0; kk < H / 32; ++kk) {
        union { bf16x8 v; unsigned long long q[2]; } hu;
        hu.q[0] = __hip_atomic_load((const unsigned long long*)(hrow + kk * 32), __ATOMIC_RELAXED, __HIP_MEMORY_SCOPE_AGENT);
        hu.q[1] = __hip_atomic_load((const unsigned long long*)(hrow + kk * 32 + 4), __ATOMIC_RELAXED, __HIP_MEMORY_SCOPE_AGENT);
        hreg[kk] = hu.v;
      }
      const int sw = (r16 & 7) << 4;
      #pragma unroll
      for (int kk = 0; kk < H / 32; ++kk) {
        bf16x8 w0 = *(const bf16x8*)((const char*)Wl + ((((0 * 16 + r16) * H + kk * 32 + kg * 8) * 2) ^ sw));
        bf16x8 w1 = *(const bf16x8*)((const char*)Wl + ((((1 * 16 + r16) * H + kk * 32 + kg * 8) * 2) ^ sw));
        bf16x8 w2 = *(const bf16x8*)((const char*)Wl + ((((2 * 16 + r16) * H + kk * 32 + kg * 8) * 2) ^ sw));
        bf16x8 w3 = *(const bf16x8*)((const char*)Wl + ((((3 * 16 + r16) * H + kk * 32 + kg * 8) * 2) ^ sw));
        A0 = __builtin_amdgcn_mfma_f32_16x16x32_bf16(hreg[kk], w0, A0, 0, 0, 0);
        A1 = __builtin_amdgcn_mfma_f32_16x16x32_bf16(hreg[kk], w1, A1, 0, 0, 0);
        A2 = __builtin_amdgcn_mfma_f32_16x16x32_bf16(hreg[kk], w2, A2, 0, 0, 0);
        A3 = __builtin_amdgcn_mfma_f32_16x16x32_bf16(hreg[kk], w3, A3, 0, 0, 0);
      }
      const int t = dir ? (TT - 1 - s) : s;
      const int batch0 = bt * 16 + kg * 4;
      unsigned short* hw = hbuf + ((size_t)(p ^ 1) * 2 + dir) * 64 * H;
      unsigned short hbv[4];
      #pragma unroll
      for (int rr = 0; rr < 4; ++rr) {
        float cn = sigf(A1[rr]) * creg[rr] + sigf(A0[rr]) * tanhfast(A2[rr]);
        float hn = sigf(A3[rr]) * tanhfast(cn);
        creg[rr] = cn;
        hbv[rr] = f2bf(hn);
        __hip_atomic_store(hw + (size_t)(batch0 + rr) * H + ug * 16 + r16, hbv[rr],
                           __ATOMIC_RELAXED, __HIP_MEMORY_SCOPE_AGENT);
      }
      asm volatile("s_waitcnt vmcnt(0)" ::: "memory");
      if (lane == 0) {
        unsigned old = __hip_atomic_fetch_add(&done[p], 1u, __ATOMIC_ACQ_REL, __HIP_MEMORY_SCOPE_WORKGROUP);
        if (old == 3u) {
          done[p] = 0u;
          __hip_atomic_store(arr + ((size_t)dir * NBLKD + ug) * 4, (unsigned)(s + 1),
                             __ATOMIC_RELAXED, __HIP_MEMORY_SCOPE_AGENT);
        }
      }
      #pragma unroll
      for (int rr = 0; rr < 4; ++rr)
        outp[((size_t)t * 64 + batch0 + rr) * (2 * H) + dir * H + ug * 16 + r16] = hbv[rr];
    }
  }
}

// ---- logits = out2 @ lin_w^T + lin_b ----
__global__ __launch_bounds__(256) void k_linear(const unsigned short* __restrict__ out2,
                                                const unsigned short* __restrict__ wl,
                                                const float* __restrict__ lb,
                                                float* __restrict__ logits) {
  const int wid = blockIdx.x * 4 + (threadIdx.x >> 6);
  const int lane = threadIdx.x & 63;
  const int mt = wid / 3, nt = wid % 3;
  const int r16 = lane & 15, kg = lane >> 4;
  const unsigned short* ar = out2 + ((size_t)mt * 16 + r16) * 512 + kg * 8;
  const unsigned short* br = wl + ((size_t)(nt * 16 + r16)) * 512 + kg * 8;
  f32x4 acc = {0.f, 0.f, 0.f, 0.f};
  #pragma unroll
  for (int kk = 0; kk < 16; ++kk) {
    bf16x8 av = *(const bf16x8*)(ar + kk * 32);
    bf16x8 bv = *(const bf16x8*)(br + kk * 32);
    acc = __builtin_amdgcn_mfma_f32_16x16x32_bf16(av, bv, acc, 0, 0, 0);
  }
  const int col = nt * 16 + r16;
  const float bias = lb[col];
  #pragma unroll
  for (int rr = 0; rr < 4; ++rr) {
    const int m = mt * 16 + kg * 4 + rr;
    logits[(size_t)m * 48 + col] = acc[rr] + bias;
  }
}

// ---- CRF partition ----
__global__ void k_crf_part(const float* __restrict__ logits, const float* __restrict__ trans,
                           const float* __restrict__ start, const float* __restrict__ endt,
                           float* __restrict__ logz) {
  const int b = blockIdx.x;
  const int j = threadIdx.x;
  __shared__ __align__(16) float alpha[2][NTAGS];
  float trj[NTAGS];
  if (j < NTAGS) {
    #pragma unroll
    for (int i = 0; i < NTAGS; ++i) trj[i] = trans[i * NTAGS + j];
    alpha[0][j] = start[j] + logits[(size_t)b * NTAGS + j];
  }
  float cur = (j < NTAGS) ? logits[((size_t)1 * BB + b) * NTAGS + j] : 0.f;
  __syncthreads();
  for (int t = 1; t < TT; ++t) {
    float nxt = (j < NTAGS && t + 1 < TT) ? logits[((size_t)(t + 1) * BB + b) * NTAGS + j] : 0.f;
    const int p = (t - 1) & 1;
    float newv = 0.f;
    if (j < NTAGS) {
      float v[NTAGS];
      const float4* ap = (const float4*)&alpha[p][0];
      #pragma unroll
      for (int q = 0; q < NTAGS / 4; ++q) {
        float4 v4 = ap[q];
        v[4 * q + 0] = v4.x + trj[4 * q + 0];
        v[4 * q + 1] = v4.y + trj[4 * q + 1];
        v[4 * q + 2] = v4.z + trj[4 * q + 2];
        v[4 * q + 3] = v4.w + trj[4 * q + 3];
      }
      float m0[24], m1[12], m2[6], m3[3];
      #pragma unroll
      for (int i = 0; i < 24; ++i) m0[i] = fmaxf(v[2 * i], v[2 * i + 1]);
      #pragma unroll
      for (int i = 0; i < 12; ++i) m1[i] = fmaxf(m0[2 * i], m0[2 * i + 1]);
      #pragma unroll
      for (int i = 0; i < 6; ++i) m2[i] = fmaxf(m1[2 * i], m1[2 * i + 1]);
      #pragma unroll
      for (int i = 0; i < 3; ++i) m3[i] = fmaxf(m2[2 * i], m2[2 * i + 1]);
      const float m = fmaxf(fmaxf(m3[0], m3[1]), m3[2]);
      float e[NTAGS];
      #pragma unroll
      for (int i = 0; i < NTAGS; ++i) e[i] = __expf(v[i] - m);
      float s0[24], s1[12], s2[6], s3[3];
      #pragma unroll
      for (int i = 0; i < 24; ++i) s0[i] = e[2 * i] + e[2 * i + 1];
      #pragma unroll
      for (int i = 0; i < 12; ++i) s1[i] = s0[2 * i] + s0[2 * i + 1];
      #pragma unroll
      for (int i = 0; i < 6; ++i) s2[i] = s1[2 * i] + s1[2 * i + 1];
      #pragma unroll
      for (int i = 0; i < 3; ++i) s3[i] = s2[2 * i] + s2[2 * i + 1];
      const float ssum = s3[0] + s3[1] + s3[2];
      newv = m + __logf(ssum) + cur;
    }
    if (j < NTAGS) alpha[p ^ 1][j] = newv;
    __syncthreads();
    cur = nxt;
  }
  float vfin = (j < NTAGS) ? alpha[(TT - 1) & 1][j] + endt[j] : -1e30f;
  float m = vfin;
  for (int o = 32; o; o >>= 1) m = fmaxf(m, __shfl_xor(m, o));
  float e = (j < NTAGS) ? __expf(vfin - m) : 0.f;
  for (int o = 32; o; o >>= 1) e += __shfl_xor(e, o);
  if (j == 0) logz[b] = m + __logf(e);
}

__global__ void k_crf_joint(const float* __restrict__ logits, const int* __restrict__ tags,
                            const float* __restrict__ trans, const float* __restrict__ start,
                            const float* __restrict__ endt, float* __restrict__ joint) {
  const int b = blockIdx.x;
  const int tid = threadIdx.x;
  float p = 0.f;
  for (int t = tid; t < TT - 1; t += 64) {
    const int tt = tags[b * TT + t], tn = tags[b * TT + t + 1];
    p += trans[tt * NTAGS + tn] + logits[((size_t)t * BB + b) * 48 + tt];
  }
  for (int o = 32; o; o >>= 1) p += __shfl_xor(p, o);
  if (tid == 0) {
    const int t0 = tags[b * TT];
    const int tl = tags[b * TT + TT - 1];
    p += start[t0] + endt[tl] + logits[((size_t)(TT - 1) * BB + b) * 48 + tl];
    joint[b] = p;
  }
}

__global__ void k_final(const float* __restrict__ joint, const float* __restrict__ logz,
                        float* __restrict__ out) {
  const int tid = threadIdx.x;
  float v = joint[tid] - logz[tid];
  for (int o = 32; o; o >>= 1) v += __shfl_xor(v, o);
  if (tid == 0) out[0] = -v;
}

// ---- workspace layout (bytes) ----
#define X_OFF    ((size_t)0)              // 33,554,432
#define WIH1_OFF ((size_t)33554432)       //  4,194,304
#define WHH1_OFF ((size_t)37748736)       //  4,194,304
#define WIH2_OFF ((size_t)41943040)       //  4,194,304
#define WHH2_OFF ((size_t)46137344)       //  1,048,576
#define WL_OFF   ((size_t)47185920)       //     49,152
#define BS1_OFF  ((size_t)47235072)       //     16,384
#define BS2_OFF  ((size_t)47251456)       //      8,192
#define OUT1_OFF ((size_t)47259648)       // 67,108,864
#define OUT2_OFF ((size_t)114368512)      // 33,554,432
#define LG_OFF   ((size_t)147922944)      //  6,291,456
#define HB1_OFF  ((size_t)154214400)      //    262,144
#define HB2_OFF  ((size_t)154476544)      //    131,072
#define LZ_OFF   ((size_t)154607616)      //        256
#define JT_OFF   ((size_t)154607872)      //        256
#define BAR_OFF  ((size_t)154608128)      //     16,384
#define WS_NEED  ((size_t)154624512)
#define CB1_OFF  ((size_t)154624512)      //    262,144
#define CB2_OFF  ((size_t)154886656)      //    131,072
#define XP_OFF   ((size_t)155017728)
#define WS_C64   ((size_t)(XP_OFF + 33554432))   // 188,572,160 (proven available)
#define WS_C128  ((size_t)(XP_OFF + 67108864))   // 222,126,592 (proven: r13 big path ran)

extern "C" void kernel_launch(void* const* d_in, const int* in_sizes, int n_in,
                              void* d_out, int out_size, void* d_ws, size_t ws_size,
                              hipStream_t stream) {
  if (ws_size < WS_NEED) return;
  const int*   seq    = (const int*)d_in[0];
  const int*   tags   = (const int*)d_in[1];
  const float* h0     = (const float*)d_in[3];
  const float* c0     = (const float*)d_in[4];
  const float* h1     = (const float*)d_in[5];
  const float* c1     = (const float*)d_in[6];
  const float* emb    = (const float*)d_in[7];
  const float* lin_w  = (const float*)d_in[8];
  const float* lin_b  = (const float*)d_in[9];
  const float* trans  = (const float*)d_in[10];
  const float* start_t= (const float*)d_in[11];
  const float* end_t  = (const float*)d_in[12];
  const float* wih1f  = (const float*)d_in[13];
  const float* whh1f  = (const float*)d_in[14];
  const float* bih1f  = (const float*)d_in[15];
  const float* bhh1f  = (const float*)d_in[16];
  const float* wih1b  = (const float*)d_in[17];
  const float* whh1b  = (const float*)d_in[18];
  const float* bih1b  = (const float*)d_in[19];
  const float* bhh1b  = (const float*)d_in[20];
  const float* wih2f  = (const float*)d_in[21];
  const float* whh2f  = (const float*)d_in[22];
  const float* bih2f  = (const float*)d_in[23];
  const float* bhh2f  = (const float*)d_in[24];
  const float* wih2b  = (const float*)d_in[25];
  const float* whh2b  = (const float*)d_in[26];
  const float* bih2b  = (const float*)d_in[27];
  const float* bhh2b  = (const float*)d_in[28];

  char* ws = (char*)d_ws;
  unsigned short* x    = (unsigned short*)(ws + X_OFF);
  unsigned short* Wih1 = (unsigned short*)(ws + WIH1_OFF);
  unsigned short* Whh1 = (unsigned short*)(ws + WHH1_OFF);
  unsigned short* Wih2 = (unsigned short*)(ws + WIH2_OFF);
  unsigned short* Whh2 = (unsigned short*)(ws + WHH2_OFF);
  unsigned short* WL   = (unsigned short*)(ws + WL_OFF);
  float*          bs1  = (float*)(ws + BS1_OFF);
  float*          bs2  = (float*)(ws + BS2_OFF);
  unsigned short* out1 = (unsigned short*)(ws + OUT1_OFF);
  unsigned short* out2 = (unsigned short*)(ws + OUT2_OFF);
  float*          lg   = (float*)(ws + LG_OFF);
  unsigned short* hb1  = (unsigned short*)(ws + HB1_OFF);
  unsigned short* hb2  = (unsigned short*)(ws + HB2_OFF);
  float*          lz   = (float*)(ws + LZ_OFF);
  float*          jt   = (float*)(ws + JT_OFF);
  unsigned*       bars = (unsigned*)(ws + BAR_OFF);
  const bool chunked = ws_size >= WS_C64;
  const bool big     = ws_size >= WS_C128;
  float*          cb1  = chunked ? (float*)(ws + CB1_OFF) : (float*)(ws + LG_OFF);
  float*          cb2  = chunked ? (float*)(ws + CB2_OFF) : (float*)(ws + LG_OFF + 262144);
  unsigned short* xp   = chunked ? (unsigned short*)(ws + XP_OFF) : nullptr;

  hipMemsetAsync(bars, 0, 16384, stream);

  k_gather_x<<<16384, 256, 0, stream>>>(emb, seq, x);
  k_conv<<<1024, 256, 0, stream>>>(wih1f, Wih1,                 262144);
  k_conv<<<1024, 256, 0, stream>>>(wih1b, Wih1 + 2048 * 512,    262144);
  k_conv<<<1024, 256, 0, stream>>>(whh1f, Whh1,                 262144);
  k_conv<<<1024, 256, 0, stream>>>(whh1b, Whh1 + 2048 * 512,    262144);
  k_conv<<<1024, 256, 0, stream>>>(wih2f, Wih2,                 262144);
  k_conv<<<1024, 256, 0, stream>>>(wih2b, Wih2 + 1024 * 1024,   262144);
  k_conv<<<256, 256, 0, stream>>>(whh2f, Whh2,                  65536);
  k_conv<<<256, 256, 0, stream>>>(whh2b, Whh2 + 1024 * 256,     65536);
  k_conv<<<24, 256, 0, stream>>>(lin_w, WL,                     6144);
  k_misc2<<<792, 256, 0, stream>>>(h0, h1, c0, c1, bih1f, bhh1f, bih1b, bhh1b,
                                   bih2f, bhh2f, bih2b, bhh2b, bs1, bs2, hb1, hb2, cb1, cb2);

  if (big) {
    for (int c = 0; c < 4; ++c) {
      k_xproj_c<512, 512><<<4096, 512, 0, stream>>>(x, Wih1, bs1, xp, c * 128);
      k_lstm_c<512, 32, 128><<<64, 256, 0, stream>>>(xp, Whh1, cb1, hb1, out1, bars, c * 128);
    }
    for (int c = 0; c < 4; ++c) {
      k_xproj_c<1024, 256><<<2048, 512, 0, stream>>>(out1, Wih2, bs2, xp, c * 128);
      k_lstm_c<256, 16, 128><<<32, 256, 0, stream>>>(xp, Whh2, cb2, hb2, out2, bars + 2048, c * 128);
    }
  } else if (chunked) {
    for (int c = 0; c < 8; ++c) {
      k_xproj_c<512, 512><<<2048, 512, 0, stream>>>(x, Wih1, bs1, xp, c * 64);
      k_lstm_c<512, 32, 64><<<64, 256, 0, stream>>>(xp, Whh1, cb1, hb1, out1, bars, c * 64);
    }
    for (int c = 0; c < 8; ++c) {
      k_xproj_c<1024, 256><<<1024, 512, 0, stream>>>(out1, Wih2, bs2, xp, c * 64);
      k_lstm_c<256, 16, 64><<<32, 256, 0, stream>>>(xp, Whh2, cb2, hb2, out2, bars + 2048, c * 64);
    }
  } else {
    k_lstm<512, 512, 32><<<64, 512, 0, stream>>>(x, Wih1, Whh1, bs1, c0, hb1, out1, bars);
    k_lstm<1024, 256, 16><<<32, 512, 0, stream>>>(out1, Wih2, Whh2, bs2, c1, hb2, out2, bars + 1024);
  }

  k_linear<<<1536, 256, 0, stream>>>(out2, WL, lin_b, lg);
  k_crf_part<<<64, 64, 0, stream>>>(lg, trans, start_t, end_t, lz);
  k_crf_joint<<<64, 64, 0, stream>>>(lg, tags, trans, start_t, end_t, jt);
  k_final<<<1, 64, 0, stream>>>(jt, lz, (float*)d_out);
}

// Round 15
// 7548.837 us; speedup vs baseline: 1.1104x; 1.1104x over previous
//
#include <hip/hip_runtime.h>
#include <stdint.h>

#define TT 512
#define BB 64
#define NTAGS 48

typedef __attribute__((ext_vector_type(8))) short bf16x8;
typedef __attribute__((ext_vector_type(4))) float f32x4;
typedef __attribute__((ext_vector_type(4))) unsigned short u16x4;

__device__ inline unsigned short f2bf(float f) {
  union { float f; unsigned u; } v; v.f = f;
  unsigned r = v.u + 0x7fffu + ((v.u >> 16) & 1u);
  return (unsigned short)(r >> 16);
}
__device__ inline float bf2f(unsigned short u) {
  union { unsigned u; float f; } v; v.u = ((unsigned)u) << 16; return v.f;
}
__device__ inline float sigf(float x) { return 1.0f / (1.0f + __expf(-x)); }
__device__ inline float tanhfast(float x) { return 1.0f - 2.0f / (__expf(2.0f * x) + 1.0f); }

// ---- x[t][b][k] = bf16(embed[seq[b][t]][k]) ----
__global__ void k_gather_x(const float* __restrict__ emb, const int* __restrict__ seq,
                           unsigned short* __restrict__ x) {
  size_t i4 = ((size_t)blockIdx.x * 256 + threadIdx.x) * 4;  // < T*B*512
  int r = (int)(i4 >> 9);
  int k = (int)(i4 & 511);
  int t = r >> 6, b = r & 63;
  int tok = seq[b * TT + t];
  float4 v = *(const float4*)(emb + (size_t)tok * 512 + k);
  unsigned short* dst = x + i4;
  dst[0] = f2bf(v.x); dst[1] = f2bf(v.y); dst[2] = f2bf(v.z); dst[3] = f2bf(v.w);
}

// ---- generic f32 -> bf16 convert, 4 elems/thread ----
__global__ void k_conv(const float* __restrict__ s, unsigned short* __restrict__ d, int n4) {
  int i = blockIdx.x * 256 + threadIdx.x;
  if (i >= n4) return;
  float4 v = *(const float4*)(s + (size_t)i * 4);
  unsigned short* dst = d + (size_t)i * 4;
  dst[0] = f2bf(v.x); dst[1] = f2bf(v.y); dst[2] = f2bf(v.z); dst[3] = f2bf(v.w);
}

// ---- bias sums + initial h (bf16 parity-0) + initial c (f32 cbuf) ----
__global__ void k_misc2(const float* __restrict__ h0, const float* __restrict__ h1,
                        const float* __restrict__ c0, const float* __restrict__ c1,
                        const float* __restrict__ bi1f, const float* __restrict__ bh1f,
                        const float* __restrict__ bi1b, const float* __restrict__ bh1b,
                        const float* __restrict__ bi2f, const float* __restrict__ bh2f,
                        const float* __restrict__ bi2b, const float* __restrict__ bh2b,
                        float* __restrict__ bs1, float* __restrict__ bs2,
                        unsigned short* __restrict__ hb1, unsigned short* __restrict__ hb2,
                        float* __restrict__ cb1, float* __restrict__ cb2) {
  int i = blockIdx.x * 256 + threadIdx.x;
  if (i < 4096) { int dd = i >> 11, n = i & 2047; bs1[i] = dd ? (bi1b[n] + bh1b[n]) : (bi1f[n] + bh1f[n]); return; }
  i -= 4096;
  if (i < 2048) { int dd = i >> 10, n = i & 1023; bs2[i] = dd ? (bi2b[n] + bh2b[n]) : (bi2f[n] + bh2f[n]); return; }
  i -= 2048;
  if (i < 65536) { hb1[i] = f2bf(h0[i]); return; }   // hbuf1 parity 0: [2][64][512]
  i -= 65536;
  if (i < 32768) { hb2[i] = f2bf(h1[i]); return; }   // hbuf2 parity 0: [2][64][256]
  i -= 32768;
  if (i < 65536) { cb1[i] = c0[i]; return; }         // cbuf1: [2][64][512]
  i -= 65536;
  if (i < 32768) { cb2[i] = c1[i]; return; }         // cbuf2: [2][64][256]
}

// ======================= PRIMARY PATH (chunked xp) =======================
// xp[sc][dir][ug][g][bt][lane*4+rr] bf16, bias folded in.  8KB per (sc,dir,ug).
template<int KX, int H>
__global__ __launch_bounds__(512) void k_xproj_c(
    const unsigned short* __restrict__ xin, const unsigned short* __restrict__ Wih,
    const float* __restrict__ bsum, unsigned short* __restrict__ xp, int s0) {
  const int UG = H / 16;
  int wid = blockIdx.x * 8 + (threadIdx.x >> 6);
  const int lane = threadIdx.x & 63;
  const int ug = wid % UG; wid /= UG;
  const int g = wid & 3; wid >>= 2;
  const int dir = wid & 1; wid >>= 1;
  const int sc = wid;
  const int s = s0 + sc;
  const int t = dir ? (TT - 1 - s) : s;
  const int r16 = lane & 15, kg = lane >> 4;
  const int rowg = dir * 4 * H + g * H + ug * 16 + r16;
  const unsigned short* wrow = Wih + (size_t)rowg * KX + kg * 8;
  const float bias = bsum[rowg];
  const unsigned short* xa = xin + (size_t)t * 64 * KX + kg * 8;
  f32x4 A0 = {bias, bias, bias, bias}, A1 = A0, A2 = A0, A3 = A0;
  #pragma unroll
  for (int kc = 0; kc < KX / 128; ++kc) {
    bf16x8 wv_[4], av_[4][4];
    #pragma unroll
    for (int u = 0; u < 4; ++u) {
      const int kk = kc * 4 + u;
      wv_[u] = *(const bf16x8*)(wrow + kk * 32);
      av_[u][0] = *(const bf16x8*)(xa + (size_t)(0 * 16 + r16) * KX + kk * 32);
      av_[u][1] = *(const bf16x8*)(xa + (size_t)(1 * 16 + r16) * KX + kk * 32);
      av_[u][2] = *(const bf16x8*)(xa + (size_t)(2 * 16 + r16) * KX + kk * 32);
      av_[u][3] = *(const bf16x8*)(xa + (size_t)(3 * 16 + r16) * KX + kk * 32);
    }
    #pragma unroll
    for (int u = 0; u < 4; ++u) {
      A0 = __builtin_amdgcn_mfma_f32_16x16x32_bf16(av_[u][0], wv_[u], A0, 0, 0, 0);
      A1 = __builtin_amdgcn_mfma_f32_16x16x32_bf16(av_[u][1], wv_[u], A1, 0, 0, 0);
      A2 = __builtin_amdgcn_mfma_f32_16x16x32_bf16(av_[u][2], wv_[u], A2, 0, 0, 0);
      A3 = __builtin_amdgcn_mfma_f32_16x16x32_bf16(av_[u][3], wv_[u], A3, 0, 0, 0);
    }
  }
  unsigned short* dst = xp + ((((size_t)sc * 2 + dir) * UG + ug) * 4 + g) * 1024 + lane * 4;
  u16x4 s0v = {f2bf(A0[0]), f2bf(A0[1]), f2bf(A0[2]), f2bf(A0[3])};
  u16x4 s1v = {f2bf(A1[0]), f2bf(A1[1]), f2bf(A1[2]), f2bf(A1[3])};
  u16x4 s2v = {f2bf(A2[0]), f2bf(A2[1]), f2bf(A2[2]), f2bf(A2[3])};
  u16x4 s3v = {f2bf(A3[0]), f2bf(A3[1]), f2bf(A3[2]), f2bf(A3[3])};
  *(u16x4*)(dst + 0)   = s0v;
  *(u16x4*)(dst + 256) = s1v;
  *(u16x4*)(dst + 512) = s2v;
  *(u16x4*)(dst + 768) = s3v;
}

// ---- recurrent chunk kernel (r13 base): decoupled waves, LDS Whh,
//      + pipelined flag poll (2-deep, no sleep) + 16B coherent h loads.
template<int H, int NBLKD, int CHN>
__global__ __launch_bounds__(256, 1) void k_lstm_c(
    const unsigned short* __restrict__ xp,    // [CHN][2][UG][4][4][256] bf16
    const unsigned short* __restrict__ Whh,   // [2][4H][H] bf16
    float* __restrict__ cbuf,                 // [2][64][H] f32 (chunk handoff)
    unsigned short* __restrict__ hbuf,        // [2 parity][2 dir][64][H] bf16
    unsigned short* __restrict__ outp,        // [T][64][2H] bf16
    unsigned* __restrict__ arr, int s0) {     // [2 dir][4 bt][NBLKD] flags (16B stride)
  const int UG = H / 16;
  const int dir = blockIdx.x / NBLKD;
  const int ug  = blockIdx.x % NBLKD;
  const int bt = threadIdx.x >> 6, lane = threadIdx.x & 63;
  const int r16 = lane & 15, kg = lane >> 4;

  __shared__ unsigned short Wl[64 * H];       // W_hh slice, XOR-swizzled (read-only in loop)
  for (int c = threadIdx.x; c < 64 * (H / 8); c += 256) {
    const int lrow = c / (H / 8), k8 = c % (H / 8);
    bf16x8 v = *(const bf16x8*)(Whh + ((size_t)(dir * 4 * H + (lrow >> 4) * H + ug * 16 + (lrow & 15))) * H + k8 * 8);
    const int addr = ((lrow * H + k8 * 8) * 2) ^ ((lrow & 7) << 4);
    *(bf16x8*)((char*)Wl + addr) = v;
  }

  const int batch0 = bt * 16 + kg * 4;
  float creg[4];
  #pragma unroll
  for (int rr = 0; rr < 4; ++rr)
    creg[rr] = cbuf[((size_t)dir * 64 + batch0 + rr) * H + ug * 16 + r16];

  __syncthreads();   // Wl staged; after this, waves fully decouple

  unsigned* const grp    = arr + (size_t)(dir * 4 + bt) * NBLKD * 4;  // this wave's flag group
  unsigned* const myflag = grp + (size_t)ug * 4;

  auto xpb = [&](int sc) -> const unsigned short* {
    return xp + (((size_t)sc * 2 + dir) * UG + ug) * 4096 + bt * 256 + lane * 4;
  };
  const unsigned short* pb = xpb(0);
  u16x4 px0 = *(const u16x4*)(pb + 0);
  u16x4 px1 = *(const u16x4*)(pb + 1024);
  u16x4 px2 = *(const u16x4*)(pb + 2048);
  u16x4 px3 = *(const u16x4*)(pb + 3072);

  for (int sc = 0; sc < CHN; ++sc) {
    const int s = s0 + sc;
    const int p = s & 1;
    // gate accumulators from prefetched xproj (bias folded in)
    f32x4 A0, A1, A2, A3;
    #pragma unroll
    for (int rr = 0; rr < 4; ++rr) {
      A0[rr] = bf2f(px0[rr]);
      A1[rr] = bf2f(px1[rr]);
      A2[rr] = bf2f(px2[rr]);
      A3[rr] = bf2f(px3[rr]);
    }
    if (sc + 1 < CHN) {  // prefetch next step's xp (plain loads, L2-cacheable)
      pb = xpb(sc + 1);
      px0 = *(const u16x4*)(pb + 0);
      px1 = *(const u16x4*)(pb + 1024);
      px2 = *(const u16x4*)(pb + 2048);
      px3 = *(const u16x4*)(pb + 3072);
    }
    // ---- wait: all NBLKD producers of (dir,bt) finished step s-1 ----
    // 2-deep pipelined poll: next load in flight while testing current value.
    if (s > 0) {
      const unsigned* ap = grp + (size_t)lane * 4;
      const bool act = lane < NBLKD;
      unsigned v0 = act ? __hip_atomic_load(ap, __ATOMIC_RELAXED, __HIP_MEMORY_SCOPE_AGENT)
                        : 0xffffffffu;
      for (;;) {
        unsigned v1 = act ? __hip_atomic_load(ap, __ATOMIC_RELAXED, __HIP_MEMORY_SCOPE_AGENT)
                          : 0xffffffffu;
        if (__all(v0 >= (unsigned)s)) break;
        v0 = v1;
      }
      asm volatile("" ::: "memory");  // keep h loads below the poll
    }
    // ---- h loads for this wave's batch tile: 16B fully-coherent loads ----
    const unsigned short* hrow = hbuf + (((size_t)p * 2 + dir) * 64 + bt * 16 + r16) * H + kg * 8;
    bf16x8 hreg[H / 32];
    #pragma unroll
    for (int kk = 0; kk < H / 32; ++kk) {
      const void* pa = hrow + kk * 32;
      asm volatile("global_load_dwordx4 %0, %1, off sc0 sc1" : "=v"(hreg[kk]) : "v"(pa));
    }
    asm volatile("s_waitcnt vmcnt(0)" ::: "memory");
    __builtin_amdgcn_sched_barrier(0);   // rule #18: pin MFMAs below the waitcnt

    const int sw = (r16 & 7) << 4;
    #pragma unroll
    for (int kk = 0; kk < H / 32; ++kk) {
      bf16x8 w0 = *(const bf16x8*)((const char*)Wl + ((((0 * 16 + r16) * H + kk * 32 + kg * 8) * 2) ^ sw));
      bf16x8 w1 = *(const bf16x8*)((const char*)Wl + ((((1 * 16 + r16) * H + kk * 32 + kg * 8) * 2) ^ sw));
      bf16x8 w2 = *(const bf16x8*)((const char*)Wl + ((((2 * 16 + r16) * H + kk * 32 + kg * 8) * 2) ^ sw));
      bf16x8 w3 = *(const bf16x8*)((const char*)Wl + ((((3 * 16 + r16) * H + kk * 32 + kg * 8) * 2) ^ sw));
      A0 = __builtin_amdgcn_mfma_f32_16x16x32_bf16(hreg[kk], w0, A0, 0, 0, 0);
      A1 = __builtin_amdgcn_mfma_f32_16x16x32_bf16(hreg[kk], w1, A1, 0, 0, 0);
      A2 = __builtin_amdgcn_mfma_f32_16x16x32_bf16(hreg[kk], w2, A2, 0, 0, 0);
      A3 = __builtin_amdgcn_mfma_f32_16x16x32_bf16(hreg[kk], w3, A3, 0, 0, 0);
    }
    const int t = dir ? (TT - 1 - s) : s;
    unsigned short* hw = hbuf + ((size_t)(p ^ 1) * 2 + dir) * 64 * H;
    unsigned short hbv[4];
    #pragma unroll
    for (int rr = 0; rr < 4; ++rr) {
      float cn = sigf(A1[rr]) * creg[rr] + sigf(A0[rr]) * tanhfast(A2[rr]);
      float hn = sigf(A3[rr]) * tanhfast(cn);
      creg[rr] = cn;
      hbv[rr] = f2bf(hn);
      __hip_atomic_store(hw + (size_t)(batch0 + rr) * H + ug * 16 + r16, hbv[rr],
                         __ATOMIC_RELAXED, __HIP_MEMORY_SCOPE_AGENT);
    }
    asm volatile("s_waitcnt vmcnt(0)" ::: "memory");  // h stores at coherence point
    if (lane == 0)
      __hip_atomic_store(myflag, (unsigned)(s + 1), __ATOMIC_RELAXED, __HIP_MEMORY_SCOPE_AGENT);
    #pragma unroll
    for (int rr = 0; rr < 4; ++rr)   // outp after flag; drains overlapped next step
      outp[((size_t)t * 64 + batch0 + rr) * (2 * H) + dir * H + ug * 16 + r16] = hbv[rr];
  }
  // chunk handoff (per-wave, disjoint)
  #pragma unroll
  for (int rr = 0; rr < 4; ++rr)
    cbuf[((size_t)dir * 64 + batch0 + rr) * H + ug * 16 + r16] = creg[rr];
}

// ======================= FALLBACK PATH (round-5, proven; small ws) =======================
template<int KX, int H, int NBLKD>
__global__ __launch_bounds__(512, 2) void k_lstm(
    const unsigned short* __restrict__ xin, const unsigned short* __restrict__ Wih,
    const unsigned short* __restrict__ Whh, const float* __restrict__ bsum,
    const float* __restrict__ cinit, unsigned short* __restrict__ hbuf,
    unsigned short* __restrict__ outp, unsigned* __restrict__ arr) {
  const int dir = blockIdx.x / NBLKD;
  const int ug  = blockIdx.x % NBLKD;
  const int wv = threadIdx.x >> 6, lane = threadIdx.x & 63;
  const int r16 = lane & 15, kg = lane >> 4;
  __shared__ unsigned short Wl[64 * H];
  __shared__ float xacc[2][4][4][256];
  __shared__ unsigned done[2];
  __shared__ int ready;
  if (threadIdx.x == 0) { done[0] = 0u; done[1] = 0u; ready = -1; }
  for (int c = threadIdx.x; c < 64 * (H / 8); c += 512) {
    const int lrow = c / (H / 8), k8 = c % (H / 8);
    bf16x8 v = *(const bf16x8*)(Whh + ((size_t)(dir * 4 * H + (lrow >> 4) * H + ug * 16 + (lrow & 15))) * H + k8 * 8);
    const int addr = ((lrow * H + k8 * 8) * 2) ^ ((lrow & 7) << 4);
    *(bf16x8*)((char*)Wl + addr) = v;
  }
  float creg[4];
  auto xgemm = [&](int sn) {
    const int gg = wv - 4;
    const int rowg = dir * 4 * H + gg * H + ug * 16 + r16;
    const unsigned short* wrow = Wih + (size_t)rowg * KX + kg * 8;
    const float bias = bsum[rowg];
    const int t = dir ? (TT - 1 - sn) : sn;
    const unsigned short* xa = xin + (size_t)t * 64 * KX + kg * 8;
    f32x4 A0 = {bias, bias, bias, bias}, A1 = A0, A2 = A0, A3 = A0;
    #pragma unroll
    for (int kc = 0; kc < KX / 128; ++kc) {
      bf16x8 wv_[4], av_[4][4];
      #pragma unroll
      for (int u = 0; u < 4; ++u) {
        const int kk = kc * 4 + u;
        wv_[u] = *(const bf16x8*)(wrow + kk * 32);
        av_[u][0] = *(const bf16x8*)(xa + (size_t)(0 * 16 + r16) * KX + kk * 32);
        av_[u][1] = *(const bf16x8*)(xa + (size_t)(1 * 16 + r16) * KX + kk * 32);
        av_[u][2] = *(const bf16x8*)(xa + (size_t)(2 * 16 + r16) * KX + kk * 32);
        av_[u][3] = *(const bf16x8*)(xa + (size_t)(3 * 16 + r16) * KX + kk * 32);
      }
      #pragma unroll
      for (int u = 0; u < 4; ++u) {
        A0 = __builtin_amdgcn_mfma_f32_16x16x32_bf16(av_[u][0], wv_[u], A0, 0, 0, 0);
        A1 = __builtin_amdgcn_mfma_f32_16x16x32_bf16(av_[u][1], wv_[u], A1, 0, 0, 0);
        A2 = __builtin_amdgcn_mfma_f32_16x16x32_bf16(av_[u][2], wv_[u], A2, 0, 0, 0);
        A3 = __builtin_amdgcn_mfma_f32_16x16x32_bf16(av_[u][3], wv_[u], A3, 0, 0, 0);
      }
    }
    const int p = sn & 1;
    *(f32x4*)&xacc[p][gg][0][lane * 4] = A0;
    *(f32x4*)&xacc[p][gg][1][lane * 4] = A1;
    *(f32x4*)&xacc[p][gg][2][lane * 4] = A2;
    *(f32x4*)&xacc[p][gg][3][lane * 4] = A3;
  };
  if (wv < 4) {
    const int batch0 = wv * 16 + kg * 4;
    #pragma unroll
    for (int rr = 0; rr < 4; ++rr)
      creg[rr] = cinit[((size_t)dir * 64 + batch0 + rr) * H + ug * 16 + r16];
  } else {
    xgemm(0);
  }
  for (int s = 0; s < TT; ++s) {
    __syncthreads();
    if (wv >= 4) {
      if (s + 1 < TT) xgemm(s + 1);
    } else {
      const int p = s & 1;
      const int bt = wv;
      f32x4 A0 = *(const f32x4*)&xacc[p][0][bt][lane * 4];
      f32x4 A1 = *(const f32x4*)&xacc[p][1][bt][lane * 4];
      f32x4 A2 = *(const f32x4*)&xacc[p][2][bt][lane * 4];
      f32x4 A3 = *(const f32x4*)&xacc[p][3][bt][lane * 4];
      const unsigned short* hrow = hbuf + (((size_t)p * 2 + dir) * 64 + bt * 16 + r16) * H + kg * 8;
      if (s > 0) {
        if (wv == 0) {
          const unsigned* ap = arr + ((size_t)dir * NBLKD + lane) * 4;
          const bool act = lane < NBLKD;
          for (;;) {
            unsigned vv = act ? __hip_atomic_load(ap, __ATOMIC_RELAXED, __HIP_MEMORY_SCOPE_AGENT)
                              : 0xffffffffu;
            if (__all(vv >= (unsigned)s)) break;
            __builtin_amdgcn_s_sleep(4);
          }
          if (lane == 0) __hip_atomic_store(&ready, s, __ATOMIC_RELAXED, __HIP_MEMORY_SCOPE_WORKGROUP);
        } else {
          while (__hip_atomic_load(&ready, __ATOMIC_RELAXED, __HIP_MEMORY_SCOPE_WORKGROUP) < s)
            __builtin_amdgcn_s_sleep(1);
        }
        asm volatile("" ::: "memory");
      }
      bf16x8 hreg[H / 32];
      #pragma unroll
      for (int kk = 0; kk < H / 32; ++kk) {
        union { bf16x8 v; unsigned long long q[2]; } hu;
        hu.q[0] = __hip_atomic_load((const unsigned long long*)(hrow + kk * 32), __ATOMIC_RELAXED, __HIP_MEMORY_SCOPE_AGENT);
        hu.q[1] = __hip_atomic_load((const unsigned long long*)(hrow + kk * 32 + 4), __ATOMIC_RELAXED, __HIP_MEMORY_SCOPE_AGENT);
        hreg[kk] = hu.v;
      }
      const int sw = (r16 & 7) << 4;
      #pragma unroll
      for (int kk = 0; kk < H / 32; ++kk) {
        bf16x8 w0 = *(const bf16x8*)((const char*)Wl + ((((0 * 16 + r16) * H + kk * 32 + kg * 8) * 2) ^ sw));
        bf16x8 w1 = *(const bf16x8*)((const char*)Wl + ((((1 * 16 + r16) * H + kk * 32 + kg * 8) * 2) ^ sw));
        bf16x8 w2 = *(const bf16x8*)((const char*)Wl + ((((2 * 16 + r16) * H + kk * 32 + kg * 8) * 2) ^ sw));
        bf16x8 w3 = *(const bf16x8*)((const char*)Wl + ((((3 * 16 + r16) * H + kk * 32 + kg * 8) * 2) ^ sw));
        A0 = __builtin_amdgcn_mfma_f32_16x16x32_bf16(hreg[kk], w0, A0, 0, 0, 0);
        A1 = __builtin_amdgcn_mfma_f32_16x16x32_bf16(hreg[kk], w1, A1, 0, 0, 0);
        A2 = __builtin_amdgcn_mfma_f32_16x16x32_bf16(hreg[kk], w2, A2, 0, 0, 0);
        A3 = __builtin_amdgcn_mfma_f32_16x16x32_bf16(hreg[kk], w3, A3, 0, 0, 0);
      }
      const int t = dir ? (TT - 1 - s) : s;
      const int batch0 = bt * 16 + kg * 4;
      unsigned short* hw = hbuf + ((size_t)(p ^ 1) * 2 + dir) * 64 * H;
      unsigned short hbv[4];
      #pragma unroll
      for (int rr = 0; rr < 4; ++rr) {
        float cn = sigf(A1[rr]) * creg[rr] + sigf(A0[rr]) * tanhfast(A2[rr]);
        float hn = sigf(A3[rr]) * tanhfast(cn);
        creg[rr] = cn;
        hbv[rr] = f2bf(hn);
        __hip_atomic_store(hw + (size_t)(batch0 + rr) * H + ug * 16 + r16, hbv[rr],
                           __ATOMIC_RELAXED, __HIP_MEMORY_SCOPE_AGENT);
      }
      asm volatile("s_waitcnt vmcnt(0)" ::: "memory");
      if (lane == 0) {
        unsigned old = __hip_atomic_fetch_add(&done[p], 1u, __ATOMIC_ACQ_REL, __HIP_MEMORY_SCOPE_WORKGROUP);
        if (old == 3u) {
          done[p] = 0u;
          __hip_atomic_store(arr + ((size_t)dir * NBLKD + ug) * 4, (unsigned)(s + 1),
                             __ATOMIC_RELAXED, __HIP_MEMORY_SCOPE_AGENT);
        }
      }
      #pragma unroll
      for (int rr = 0; rr < 4; ++rr)
        outp[((size_t)t * 64 + batch0 + rr) * (2 * H) + dir * H + ug * 16 + r16] = hbv[rr];
    }
  }
}

// ---- logits = out2 @ lin_w^T + lin_b ----
__global__ __launch_bounds__(256) void k_linear(const unsigned short* __restrict__ out2,
                                                const unsigned short* __restrict__ wl,
                                                const float* __restrict__ lb,
                                                float* __restrict__ logits) {
  const int wid = blockIdx.x * 4 + (threadIdx.x >> 6);
  const int lane = threadIdx.x & 63;
  const int mt = wid / 3, nt = wid % 3;
  const int r16 = lane & 15, kg = lane >> 4;
  const unsigned short* ar = out2 + ((size_t)mt * 16 + r16) * 512 + kg * 8;
  const unsigned short* br = wl + ((size_t)(nt * 16 + r16)) * 512 + kg * 8;
  f32x4 acc = {0.f, 0.f, 0.f, 0.f};
  #pragma unroll
  for (int kk = 0; kk < 16; ++kk) {
    bf16x8 av = *(const bf16x8*)(ar + kk * 32);
    bf16x8 bv = *(const bf16x8*)(br + kk * 32);
    acc = __builtin_amdgcn_mfma_f32_16x16x32_bf16(av, bv, acc, 0, 0, 0);
  }
  const int col = nt * 16 + r16;
  const float bias = lb[col];
  #pragma unroll
  for (int rr = 0; rr < 4; ++rr) {
    const int m = mt * 16 + kg * 4 + rr;
    logits[(size_t)m * 48 + col] = acc[rr] + bias;
  }
}

// ---- CRF partition ----
__global__ void k_crf_part(const float* __restrict__ logits, const float* __restrict__ trans,
                           const float* __restrict__ start, const float* __restrict__ endt,
                           float* __restrict__ logz) {
  const int b = blockIdx.x;
  const int j = threadIdx.x;
  __shared__ __align__(16) float alpha[2][NTAGS];
  float trj[NTAGS];
  if (j < NTAGS) {
    #pragma unroll
    for (int i = 0; i < NTAGS; ++i) trj[i] = trans[i * NTAGS + j];
    alpha[0][j] = start[j] + logits[(size_t)b * NTAGS + j];
  }
  float cur = (j < NTAGS) ? logits[((size_t)1 * BB + b) * NTAGS + j] : 0.f;
  __syncthreads();
  for (int t = 1; t < TT; ++t) {
    float nxt = (j < NTAGS && t + 1 < TT) ? logits[((size_t)(t + 1) * BB + b) * NTAGS + j] : 0.f;
    const int p = (t - 1) & 1;
    float newv = 0.f;
    if (j < NTAGS) {
      float v[NTAGS];
      const float4* ap = (const float4*)&alpha[p][0];
      #pragma unroll
      for (int q = 0; q < NTAGS / 4; ++q) {
        float4 v4 = ap[q];
        v[4 * q + 0] = v4.x + trj[4 * q + 0];
        v[4 * q + 1] = v4.y + trj[4 * q + 1];
        v[4 * q + 2] = v4.z + trj[4 * q + 2];
        v[4 * q + 3] = v4.w + trj[4 * q + 3];
      }
      float m0[24], m1[12], m2[6], m3[3];
      #pragma unroll
      for (int i = 0; i < 24; ++i) m0[i] = fmaxf(v[2 * i], v[2 * i + 1]);
      #pragma unroll
      for (int i = 0; i < 12; ++i) m1[i] = fmaxf(m0[2 * i], m0[2 * i + 1]);
      #pragma unroll
      for (int i = 0; i < 6; ++i) m2[i] = fmaxf(m1[2 * i], m1[2 * i + 1]);
      #pragma unroll
      for (int i = 0; i < 3; ++i) m3[i] = fmaxf(m2[2 * i], m2[2 * i + 1]);
      const float m = fmaxf(fmaxf(m3[0], m3[1]), m3[2]);
      float e[NTAGS];
      #pragma unroll
      for (int i = 0; i < NTAGS; ++i) e[i] = __expf(v[i] - m);
      float s0[24], s1[12], s2[6], s3[3];
      #pragma unroll
      for (int i = 0; i < 24; ++i) s0[i] = e[2 * i] + e[2 * i + 1];
      #pragma unroll
      for (int i = 0; i < 12; ++i) s1[i] = s0[2 * i] + s0[2 * i + 1];
      #pragma unroll
      for (int i = 0; i < 6; ++i) s2[i] = s1[2 * i] + s1[2 * i + 1];
      #pragma unroll
      for (int i = 0; i < 3; ++i) s3[i] = s2[2 * i] + s2[2 * i + 1];
      const float ssum = s3[0] + s3[1] + s3[2];
      newv = m + __logf(ssum) + cur;
    }
    if (j < NTAGS) alpha[p ^ 1][j] = newv;
    __syncthreads();
    cur = nxt;
  }
  float vfin = (j < NTAGS) ? alpha[(TT - 1) & 1][j] + endt[j] : -1e30f;
  float m = vfin;
  for (int o = 32; o; o >>= 1) m = fmaxf(m, __shfl_xor(m, o));
  float e = (j < NTAGS) ? __expf(vfin - m) : 0.f;
  for (int o = 32; o; o >>= 1) e += __shfl_xor(e, o);
  if (j == 0) logz[b] = m + __logf(e);
}

__global__ void k_crf_joint(const float* __restrict__ logits, const int* __restrict__ tags,
                            const float* __restrict__ trans, const float* __restrict__ start,
                            const float* __restrict__ endt, float* __restrict__ joint) {
  const int b = blockIdx.x;
  const int tid = threadIdx.x;
  float p = 0.f;
  for (int t = tid; t < TT - 1; t += 64) {
    const int tt = tags[b * TT + t], tn = tags[b * TT + t + 1];
    p += trans[tt * NTAGS + tn] + logits[((size_t)t * BB + b) * 48 + tt];
  }
  for (int o = 32; o; o >>= 1) p += __shfl_xor(p, o);
  if (tid == 0) {
    const int t0 = tags[b * TT];
    const int tl = tags[b * TT + TT - 1];
    p += start[t0] + endt[tl] + logits[((size_t)(TT - 1) * BB + b) * 48 + tl];
    joint[b] = p;
  }
}

__global__ void k_final(const float* __restrict__ joint, const float* __restrict__ logz,
                        float* __restrict__ out) {
  const int tid = threadIdx.x;
  float v = joint[tid] - logz[tid];
  for (int o = 32; o; o >>= 1) v += __shfl_xor(v, o);
  if (tid == 0) out[0] = -v;
}

// ---- workspace layout (bytes) ----
#define X_OFF    ((size_t)0)              // 33,554,432
#define WIH1_OFF ((size_t)33554432)       //  4,194,304
#define WHH1_OFF ((size_t)37748736)       //  4,194,304
#define WIH2_OFF ((size_t)41943040)       //  4,194,304
#define WHH2_OFF ((size_t)46137344)       //  1,048,576
#define WL_OFF   ((size_t)47185920)       //     49,152
#define BS1_OFF  ((size_t)47235072)       //     16,384
#define BS2_OFF  ((size_t)47251456)       //      8,192
#define OUT1_OFF ((size_t)47259648)       // 67,108,864
#define OUT2_OFF ((size_t)114368512)      // 33,554,432
#define LG_OFF   ((size_t)147922944)      //  6,291,456
#define HB1_OFF  ((size_t)154214400)      //    262,144
#define HB2_OFF  ((size_t)154476544)      //    131,072
#define LZ_OFF   ((size_t)154607616)      //        256
#define JT_OFF   ((size_t)154607872)      //        256
#define BAR_OFF  ((size_t)154608128)      //     16,384
#define WS_NEED  ((size_t)154624512)
#define CB1_OFF  ((size_t)154624512)      //    262,144
#define CB2_OFF  ((size_t)154886656)      //    131,072
#define XP_OFF   ((size_t)155017728)
#define WS_C64   ((size_t)(XP_OFF + 33554432))   // 188,572,160 (proven available)
#define WS_C128  ((size_t)(XP_OFF + 67108864))   // 222,126,592 (proven: r13 big path ran)

extern "C" void kernel_launch(void* const* d_in, const int* in_sizes, int n_in,
                              void* d_out, int out_size, void* d_ws, size_t ws_size,
                              hipStream_t stream) {
  if (ws_size < WS_NEED) return;
  const int*   seq    = (const int*)d_in[0];
  const int*   tags   = (const int*)d_in[1];
  const float* h0     = (const float*)d_in[3];
  const float* c0     = (const float*)d_in[4];
  const float* h1     = (const float*)d_in[5];
  const float* c1     = (const float*)d_in[6];
  const float* emb    = (const float*)d_in[7];
  const float* lin_w  = (const float*)d_in[8];
  const float* lin_b  = (const float*)d_in[9];
  const float* trans  = (const float*)d_in[10];
  const float* start_t= (const float*)d_in[11];
  const float* end_t  = (const float*)d_in[12];
  const float* wih1f  = (const float*)d_in[13];
  const float* whh1f  = (const float*)d_in[14];
  const float* bih1f  = (const float*)d_in[15];
  const float* bhh1f  = (const float*)d_in[16];
  const float* wih1b  = (const float*)d_in[17];
  const float* whh1b  = (const float*)d_in[18];
  const float* bih1b  = (const float*)d_in[19];
  const float* bhh1b  = (const float*)d_in[20];
  const float* wih2f  = (const float*)d_in[21];
  const float* whh2f  = (const float*)d_in[22];
  const float* bih2f  = (const float*)d_in[23];
  const float* bhh2f  = (const float*)d_in[24];
  const float* wih2b  = (const float*)d_in[25];
  const float* whh2b  = (const float*)d_in[26];
  const float* bih2b  = (const float*)d_in[27];
  const float* bhh2b  = (const float*)d_in[28];

  char* ws = (char*)d_ws;
  unsigned short* x    = (unsigned short*)(ws + X_OFF);
  unsigned short* Wih1 = (unsigned short*)(ws + WIH1_OFF);
  unsigned short* Whh1 = (unsigned short*)(ws + WHH1_OFF);
  unsigned short* Wih2 = (unsigned short*)(ws + WIH2_OFF);
  unsigned short* Whh2 = (unsigned short*)(ws + WHH2_OFF);
  unsigned short* WL   = (unsigned short*)(ws + WL_OFF);
  float*          bs1  = (float*)(ws + BS1_OFF);
  float*          bs2  = (float*)(ws + BS2_OFF);
  unsigned short* out1 = (unsigned short*)(ws + OUT1_OFF);
  unsigned short* out2 = (unsigned short*)(ws + OUT2_OFF);
  float*          lg   = (float*)(ws + LG_OFF);
  unsigned short* hb1  = (unsigned short*)(ws + HB1_OFF);
  unsigned short* hb2  = (unsigned short*)(ws + HB2_OFF);
  float*          lz   = (float*)(ws + LZ_OFF);
  float*          jt   = (float*)(ws + JT_OFF);
  unsigned*       bars = (unsigned*)(ws + BAR_OFF);
  const bool chunked = ws_size >= WS_C64;
  const bool big     = ws_size >= WS_C128;
  float*          cb1  = chunked ? (float*)(ws + CB1_OFF) : (float*)(ws + LG_OFF);
  float*          cb2  = chunked ? (float*)(ws + CB2_OFF) : (float*)(ws + LG_OFF + 262144);
  unsigned short* xp   = chunked ? (unsigned short*)(ws + XP_OFF) : nullptr;

  hipMemsetAsync(bars, 0, 16384, stream);

  k_gather_x<<<16384, 256, 0, stream>>>(emb, seq, x);
  k_conv<<<1024, 256, 0, stream>>>(wih1f, Wih1,                 262144);
  k_conv<<<1024, 256, 0, stream>>>(wih1b, Wih1 + 2048 * 512,    262144);
  k_conv<<<1024, 256, 0, stream>>>(whh1f, Whh1,                 262144);
  k_conv<<<1024, 256, 0, stream>>>(whh1b, Whh1 + 2048 * 512,    262144);
  k_conv<<<1024, 256, 0, stream>>>(wih2f, Wih2,                 262144);
  k_conv<<<1024, 256, 0, stream>>>(wih2b, Wih2 + 1024 * 1024,   262144);
  k_conv<<<256, 256, 0, stream>>>(whh2f, Whh2,                  65536);
  k_conv<<<256, 256, 0, stream>>>(whh2b, Whh2 + 1024 * 256,     65536);
  k_conv<<<24, 256, 0, stream>>>(lin_w, WL,                     6144);
  k_misc2<<<792, 256, 0, stream>>>(h0, h1, c0, c1, bih1f, bhh1f, bih1b, bhh1b,
                                   bih2f, bhh2f, bih2b, bhh2b, bs1, bs2, hb1, hb2, cb1, cb2);

  if (big) {
    for (int c = 0; c < 4; ++c) {
      k_xproj_c<512, 512><<<4096, 512, 0, stream>>>(x, Wih1, bs1, xp, c * 128);
      k_lstm_c<512, 32, 128><<<64, 256, 0, stream>>>(xp, Whh1, cb1, hb1, out1, bars, c * 128);
    }
    for (int c = 0; c < 4; ++c) {
      k_xproj_c<1024, 256><<<2048, 512, 0, stream>>>(out1, Wih2, bs2, xp, c * 128);
      k_lstm_c<256, 16, 128><<<32, 256, 0, stream>>>(xp, Whh2, cb2, hb2, out2, bars + 2048, c * 128);
    }
  } else if (chunked) {
    for (int c = 0; c < 8; ++c) {
      k_xproj_c<512, 512><<<2048, 512, 0, stream>>>(x, Wih1, bs1, xp, c * 64);
      k_lstm_c<512, 32, 64><<<64, 256, 0, stream>>>(xp, Whh1, cb1, hb1, out1, bars, c * 64);
    }
    for (int c = 0; c < 8; ++c) {
      k_xproj_c<1024, 256><<<1024, 512, 0, stream>>>(out1, Wih2, bs2, xp, c * 64);
      k_lstm_c<256, 16, 64><<<32, 256, 0, stream>>>(xp, Whh2, cb2, hb2, out2, bars + 2048, c * 64);
    }
  } else {
    k_lstm<512, 512, 32><<<64, 512, 0, stream>>>(x, Wih1, Whh1, bs1, c0, hb1, out1, bars);
    k_lstm<1024, 256, 16><<<32, 512, 0, stream>>>(out1, Wih2, Whh2, bs2, c1, hb2, out2, bars + 1024);
  }

  k_linear<<<1536, 256, 0, stream>>>(out2, WL, lin_b, lg);
  k_crf_part<<<64, 64, 0, stream>>>(lg, trans, start_t, end_t, lz);
  k_crf_joint<<<64, 64, 0, stream>>>(lg, tags, trans, start_t, end_t, jt);
  k_final<<<1, 64, 0, stream>>>(jt, lz, (float*)d_out);
}